// Round 3
// baseline (1296.396 us; speedup 1.0000x reference)
//
#include <hip/hip_runtime.h>

// ChunkwiseDeltaAttention (MI355X/gfx950) — round 6
// B=4 L=4096 H=2048 NH=16 D=128 C=64 -> M=16384, K=2048
//
// Fast path:
//   beta_kernel: beta = softplus(hs @ b_w^T + b_b), AND hs -> bf16 hsb (fused)
//   cvt: {q,k,v,og}_w -> bf16 wcat [8192,2048]; o_w -> owb
//   gemm256<0,8192>: [qy|kn|gv|gate] = hsb @ wcat^T (+bias), fused epi
//   attn: l2norm in LDS, S=qk^T (MFMA), causal mask, O=S gv, *gate
//   gemm256<3,2048>: out = y @ o_w^T + o_b -> f32 d_out
//
// GEMM round 6: same data plane as round 5 (256x256 tile, BK=32, 8 waves
// 2Mx4N, 4-deep LDS ring, sigma(row)=(row>>1)&3 swizzle = 0 conflicts,
// counted vmcnt(8) once per K-tile) but the compute plane is restructured
// into the verified 8-phase-style LOCKSTEP: per K-tile, TWO phases, each
//   { ds_read subtile ; stage half of tile t+3 ; s_barrier ;
//     s_waitcnt lgkmcnt(0) ; setprio(1) ; 16 MFMA ; setprio(0) ; s_barrier }
// Round-5 post-mortem: one-barrier-per-tile coarse split left MfmaUtil at
// 35% even with 0 bank conflicts (reads of both waves never hide under the
// other's MFMA; matrix pipe contended pairwise). The per-phase double
// barrier creates the load/MFMA role split that makes setprio + counted
// vmcnt pay (m196/m218b/m201 evidence chain).

typedef __bf16 bf16x8 __attribute__((ext_vector_type(8)));
typedef float f32x4 __attribute__((ext_vector_type(4)));

typedef __attribute__((address_space(1))) const unsigned int g_u32;
typedef __attribute__((address_space(3))) unsigned int l_u32;

__device__ __forceinline__ void cp16(const unsigned short* g, unsigned short* l) {
  __builtin_amdgcn_global_load_lds((g_u32*)g, (l_u32*)l, 16, 0, 0);
}

__device__ __forceinline__ unsigned short f2bf(float x) {
  unsigned u = __builtin_bit_cast(unsigned, x);
  u += 0x7fffu + ((u >> 16) & 1u);          // RNE
  return (unsigned short)(u >> 16);
}
__device__ __forceinline__ float bf2f(unsigned short h) {
  return __builtin_bit_cast(float, (unsigned)h << 16);
}
__device__ __forceinline__ unsigned pk2(float a, float b) {
  return (unsigned)f2bf(a) | ((unsigned)f2bf(b) << 16);
}

// ------------------------------------------------------------- convert ----
__global__ __launch_bounds__(256) void cvt_bf16(const float* __restrict__ in,
                                                unsigned short* __restrict__ out,
                                                int n) {
  int i = (blockIdx.x * 256 + threadIdx.x) * 8;
  if (i >= n) return;
  float4 f0 = *(const float4*)(in + i);
  float4 f1 = *(const float4*)(in + i + 4);
  uint4 u;
  u.x = pk2(f0.x, f0.y); u.y = pk2(f0.z, f0.w);
  u.z = pk2(f1.x, f1.y); u.w = pk2(f1.z, f1.w);
  *(uint4*)(out + i) = u;
}

__global__ __launch_bounds__(256) void build_bias(
    const float* __restrict__ qb, const float* __restrict__ kb,
    const float* __restrict__ vb, float* __restrict__ bias_cat) {
  int i = blockIdx.x * 256 + threadIdx.x;   // 0..8191
  float v = 0.f;
  if (i < 2048) v = qb[i];
  else if (i < 4096) v = kb[i - 2048];
  else if (i < 6144) v = vb[i - 4096];
  bias_cat[i] = v;
}

// ------------------------------------------------- beta (+ hs->bf16) ------
__global__ __launch_bounds__(256) void beta_kernel(
    const float* __restrict__ hs, const float* __restrict__ bw,
    const float* __restrict__ bb, float* __restrict__ beta,
    unsigned short* __restrict__ hsb) {
  __shared__ float row[2048];
  __shared__ float part[16][17];
  const int m = blockIdx.x;
  const float* src = hs + (size_t)m * 2048;
  for (int i = threadIdx.x; i < 512; i += 256)
    ((float4*)row)[i] = ((const float4*)src)[i];
  __syncthreads();
  if (hsb) {  // fused f32->bf16 of this row
    int e = threadIdx.x * 8;
    uint4 u;
    u.x = pk2(row[e], row[e + 1]);     u.y = pk2(row[e + 2], row[e + 3]);
    u.z = pk2(row[e + 4], row[e + 5]); u.w = pk2(row[e + 6], row[e + 7]);
    *(uint4*)(hsb + (size_t)m * 2048 + e) = u;
  }
  const int h = threadIdx.x >> 4, j = threadIdx.x & 15;
  const float* w = bw + h * 2048;
  float s = 0.f;
  #pragma unroll 8
  for (int kk = 0; kk < 128; kk++) {
    int k = j + (kk << 4);
    s += row[k] * w[k];
  }
  part[h][j] = s;
  __syncthreads();
  if (threadIdx.x < 16) {
    int hh = threadIdx.x;
    float t = bb[hh];
    #pragma unroll
    for (int j2 = 0; j2 < 16; j2++) t += part[hh][j2];
    beta[(size_t)m * 16 + hh] = fmaxf(t, 0.f) + log1pf(__expf(-fabsf(t)));
  }
}

// -------------------------------------------- GEMM 256x256, 2-phase lockstep
// C[m,n] = sum_k A[m,k]*B[n,k], bf16 in. 512 threads = 8 waves (2Mx4N).
// LDS ring: As/Bs[4 bufs][256 rows][32 cols] bf16 (16KB per matrix per buf).
// Per K-tile t (cur=t&3, nb=(t+3)&3), two lockstep phases:
//   p0: ds_read A mi0-3 + B ni0-3 (8xb128); stage A(t+3) (2 cp16);
//       barrier; lgkmcnt(0); setprio(1); 16 MFMA (acc[0..3][*]); setprio(0);
//       barrier
//   p1: ds_read A mi4-7 (4xb128, B held in regs); stage B(t+3) (2 cp16);
//       barrier; lgkmcnt(0); setprio(1); 16 MFMA (acc[4..7][*]); setprio(0);
//       vmcnt(8); barrier            (boundary: next tile may read buf cur+1)
// vmcnt proof: at the boundary of tile t, outstanding = stages for tiles
// t+1, t+2, t+3 (4 loads each, in order). vmcnt(8) drains until 8 remain
// ({t+2,t+3}) => all of t+1's loads complete before any wave reads them.
// Buffer nb=(t+3)&3 was last read at tile t-1 (before the t-1 boundary
// barrier), so staging into it during tile t is race-free.
// Tail (t+3>=NT): stage reloads of tile NT-1 into the free slot to keep the
// vmcnt literal uniform; drained by vmcnt(0) before the epilogue.
template <int EPI, int N, int K>
__global__ __launch_bounds__(512, 2) void gemm256(
    const unsigned short* __restrict__ A, const unsigned short* __restrict__ Bw,
    const float* __restrict__ bias, const float* __restrict__ beta,
    void* __restrict__ Cv) {
  constexpr int NT = K / 32;
  __shared__ __align__(16) unsigned short As[4 * 8192];
  __shared__ __align__(16) unsigned short Bs[4 * 8192];
  const int tid = threadIdx.x;
  const int m0 = blockIdx.y * 256;
  const int n0 = blockIdx.x * 256;
  const int wid = tid >> 6, lane = tid & 63;
  const int wm = wid >> 2, wn = wid & 3;
  const int quad = lane >> 4, l16 = lane & 15;

  // staging: thread t covers rows trow and trow+128, 16B chunk p=t&3 of the
  // 64B row; source column is the XOR-swizzled chunk l = p ^ ((row>>1)&3).
  // sigma(trow) == sigma(trow+128) since 128 is a multiple of 8.
  const int trow = tid >> 2;
  const int tch = (((tid & 3) ^ ((trow >> 1) & 3)) << 3);  // element offset
  const unsigned short* Ag = A + (size_t)(m0 + trow) * K + tch;
  const unsigned short* Bg = Bw + (size_t)(n0 + trow) * K + tch;

  // ds_read side: physical chunk = quad ^ ((row>>1)&3); base rows are
  // multiples of 8 so (row>>1)&3 == (l16>>1)&3 for all fragments.
  // Conflict-free (verified round 5: SQ_LDS_BANK_CONFLICT = 0).
  const int chs = ((quad ^ ((l16 >> 1) & 3)) << 4);        // byte offset
  const int a_lane = (wm * 128 + l16) * 64 + chs;
  const int b_lane = (wn * 64 + l16) * 64 + chs;

  f32x4 acc[8][4] = {};

  // prologue: stage tiles 0,1,2 (A,A,B,B per tile, in tile order)
  #pragma unroll
  for (int tt = 0; tt < 3; ++tt) {
    const size_t kk = (size_t)tt * 32;
    unsigned short* la = As + tt * 8192 + tid * 8;
    unsigned short* lb = Bs + tt * 8192 + tid * 8;
    cp16(Ag + kk, la);
    cp16(Ag + (size_t)128 * K + kk, la + 4096);
    cp16(Bg + kk, lb);
    cp16(Bg + (size_t)128 * K + kk, lb + 4096);
  }
  asm volatile("s_waitcnt vmcnt(8)" ::: "memory");   // tile 0 complete
  __builtin_amdgcn_s_barrier();

  for (int t = 0; t < NT; ++t) {
    const int cur = t & 3;
    const int nb = (t + 3) & 3;
    const size_t k3 = (size_t)((t + 3 < NT) ? (t + 3) : (NT - 1)) * 32;
    const char* At = (const char*)As + cur * 16384 + a_lane;
    const char* Bt = (const char*)Bs + cur * 16384 + b_lane;
    unsigned short* la = As + nb * 8192 + tid * 8;
    unsigned short* lb = Bs + nb * 8192 + tid * 8;

    bf16x8 af[4], bfr[4];

    // ---- phase 0: ds_read A mi0-3 + B; stage A(t+3); lockstep MFMA ----
    #pragma unroll
    for (int mi = 0; mi < 4; mi++) af[mi] = *(const bf16x8*)(At + mi * 1024);
    #pragma unroll
    for (int ni = 0; ni < 4; ni++) bfr[ni] = *(const bf16x8*)(Bt + ni * 1024);
    cp16(Ag + k3, la);
    cp16(Ag + (size_t)128 * K + k3, la + 4096);
    __builtin_amdgcn_s_barrier();
    asm volatile("s_waitcnt lgkmcnt(0)" ::: "memory");
    __builtin_amdgcn_s_setprio(1);
    #pragma unroll
    for (int mi = 0; mi < 4; mi++)
      #pragma unroll
      for (int ni = 0; ni < 4; ni++)
        acc[mi][ni] = __builtin_amdgcn_mfma_f32_16x16x32_bf16(
            af[mi], bfr[ni], acc[mi][ni], 0, 0, 0);
    __builtin_amdgcn_s_setprio(0);
    __builtin_amdgcn_s_barrier();

    // ---- phase 1: ds_read A mi4-7 (B in regs); stage B(t+3); MFMA ----
    #pragma unroll
    for (int mi = 0; mi < 4; mi++) af[mi] = *(const bf16x8*)(At + (4 + mi) * 1024);
    cp16(Bg + k3, lb);
    cp16(Bg + (size_t)128 * K + k3, lb + 4096);
    __builtin_amdgcn_s_barrier();
    asm volatile("s_waitcnt lgkmcnt(0)" ::: "memory");
    __builtin_amdgcn_s_setprio(1);
    #pragma unroll
    for (int mi = 0; mi < 4; mi++)
      #pragma unroll
      for (int ni = 0; ni < 4; ni++)
        acc[4 + mi][ni] = __builtin_amdgcn_mfma_f32_16x16x32_bf16(
            af[mi], bfr[ni], acc[4 + mi][ni], 0, 0, 0);
    __builtin_amdgcn_s_setprio(0);

    if (t != NT - 1) {
      asm volatile("s_waitcnt vmcnt(8)" ::: "memory");
      __builtin_amdgcn_s_barrier();
    }
  }
  // drain tail garbage stages before the epilogue / kernel end
  asm volatile("s_waitcnt vmcnt(0)" ::: "memory");

  // epilogue; C/D layout: col=lane&15, row=quad*4+reg
  if (EPI == 0) {
    const int mode = n0 >> 11;              // 0:q 1:k 2:v 3:gate (256 | 2048)
    unsigned short* outp =
        (unsigned short*)Cv + (size_t)mode * ((size_t)16384 * 2048);
    const int head = ((n0 + wn * 64) >> 7) & 15;   // head uniform per wave
    #pragma unroll
    for (int mi = 0; mi < 8; mi++) {
      #pragma unroll
      for (int r = 0; r < 4; r++) {
        const int row = m0 + wm * 128 + mi * 16 + quad * 4 + r;
        const float bsc = (mode == 2) ? beta[(size_t)row * 16 + head] : 1.f;
        #pragma unroll
        for (int ni = 0; ni < 4; ni++) {
          const int col = n0 + wn * 64 + ni * 16 + l16;
          float x = acc[mi][ni][r] + bias[col];
          if (mode == 2) x *= bsc;
          if (mode == 3) x = x / (1.f + __expf(-x));
          outp[(size_t)row * 2048 + (col & 2047)] = f2bf(x);
        }
      }
    }
  } else {
    #pragma unroll
    for (int mi = 0; mi < 8; mi++)
      #pragma unroll
      for (int r = 0; r < 4; r++) {
        const int row = m0 + wm * 128 + mi * 16 + quad * 4 + r;
        #pragma unroll
        for (int ni = 0; ni < 4; ni++) {
          const int col = n0 + wn * 64 + ni * 16 + l16;
          ((float*)Cv)[(size_t)row * N + col] = acc[mi][ni][r] + bias[col];
        }
      }
  }
}

// --------------------------------------------- fallback GEMM (round 1) ----
constexpr int GLDW = 40;
template <int EPI, bool ABF16>
__global__ __launch_bounds__(256) void gemm_bt(
    const void* __restrict__ Av, const float* __restrict__ Bw,
    const float* __restrict__ bias, const float* __restrict__ beta,
    void* __restrict__ Cv, int M, int N, int K) {
  __shared__ unsigned short As[128 * GLDW];
  __shared__ unsigned short Bs[128 * GLDW];
  const int tid = threadIdx.x;
  const int m0 = blockIdx.y * 128;
  const int n0 = blockIdx.x * 128;
  const int wid = tid >> 6, lane = tid & 63;
  const int wm = wid >> 1, wn = wid & 1;
  const int quad = lane >> 4, l16 = lane & 15;
  const int srow = tid >> 1, skh = (tid & 1) << 4;

  f32x4 acc[4][4] = {};
  const float* Bg = Bw + (size_t)(n0 + srow) * K + skh;

  for (int kb = 0; kb < K; kb += 32) {
    if (ABF16) {
      const unsigned short* Ag =
          (const unsigned short*)Av + (size_t)(m0 + srow) * K + kb + skh;
      uint4 u0 = ((const uint4*)Ag)[0];
      uint4 u1 = ((const uint4*)Ag)[1];
      uint4* d = (uint4*)&As[srow * GLDW + skh];
      d[0] = u0; d[1] = u1;
    } else {
      const float* Ag = (const float*)Av + (size_t)(m0 + srow) * K + kb + skh;
      float4 f0 = ((const float4*)Ag)[0];
      float4 f1 = ((const float4*)Ag)[1];
      float4 f2 = ((const float4*)Ag)[2];
      float4 f3 = ((const float4*)Ag)[3];
      unsigned* d = (unsigned*)&As[srow * GLDW + skh];
      d[0] = pk2(f0.x, f0.y); d[1] = pk2(f0.z, f0.w);
      d[2] = pk2(f1.x, f1.y); d[3] = pk2(f1.z, f1.w);
      d[4] = pk2(f2.x, f2.y); d[5] = pk2(f2.z, f2.w);
      d[6] = pk2(f3.x, f3.y); d[7] = pk2(f3.z, f3.w);
    }
    {
      const float* Bgk = Bg + kb;
      float4 f0 = ((const float4*)Bgk)[0];
      float4 f1 = ((const float4*)Bgk)[1];
      float4 f2 = ((const float4*)Bgk)[2];
      float4 f3 = ((const float4*)Bgk)[3];
      unsigned* d = (unsigned*)&Bs[srow * GLDW + skh];
      d[0] = pk2(f0.x, f0.y); d[1] = pk2(f0.z, f0.w);
      d[2] = pk2(f1.x, f1.y); d[3] = pk2(f1.z, f1.w);
      d[4] = pk2(f2.x, f2.y); d[5] = pk2(f2.z, f2.w);
      d[6] = pk2(f3.x, f3.y); d[7] = pk2(f3.z, f3.w);
    }
    __syncthreads();
    bf16x8 af[4], bfr[4];
    #pragma unroll
    for (int mi = 0; mi < 4; mi++)
      af[mi] = *(const bf16x8*)&As[(wm * 64 + mi * 16 + l16) * GLDW + (quad << 3)];
    #pragma unroll
    for (int ni = 0; ni < 4; ni++)
      bfr[ni] = *(const bf16x8*)&Bs[(wn * 64 + ni * 16 + l16) * GLDW + (quad << 3)];
    #pragma unroll
    for (int mi = 0; mi < 4; mi++)
      #pragma unroll
      for (int ni = 0; ni < 4; ni++)
        acc[mi][ni] = __builtin_amdgcn_mfma_f32_16x16x32_bf16(
            af[mi], bfr[ni], acc[mi][ni], 0, 0, 0);
    __syncthreads();
  }

  #pragma unroll
  for (int mi = 0; mi < 4; mi++) {
    #pragma unroll
    for (int r = 0; r < 4; r++) {
      const int row = m0 + wm * 64 + mi * 16 + quad * 4 + r;
      float bsc = 1.f;
      if (EPI == 1) bsc = beta[(size_t)row * 16 + blockIdx.x];
      #pragma unroll
      for (int ni = 0; ni < 4; ni++) {
        const int col = n0 + wn * 64 + ni * 16 + l16;
        float x = acc[mi][ni][r];
        if (EPI != 2) x += bias[col];
        if (EPI == 1) x *= bsc;
        if (EPI == 2) x = x / (1.f + __expf(-x));
        if (EPI == 3)
          ((float*)Cv)[(size_t)row * N + col] = x;
        else
          ((unsigned short*)Cv)[(size_t)row * N + col] = f2bf(x);
      }
    }
  }
}

// ----------------------------------------------------------- attention ----
constexpr int QK_LDW = 132;  // 264B = 66 banks = 2 mod 32: lanes spread
constexpr int GT_LDW = 66;   // 132B = 33 banks = 1 mod 32: write 16-way -> 4-way
constexpr int SS_LDW = 68;   // 136B = 34 banks = 2 mod 32

__global__ __launch_bounds__(256) void attn_kernel(
    const unsigned short* __restrict__ qn, const unsigned short* __restrict__ kn,
    const unsigned short* __restrict__ gvp, const unsigned short* __restrict__ gate,
    unsigned short* __restrict__ y) {
  __shared__ unsigned short qs[64 * QK_LDW];
  __shared__ unsigned short ks[64 * QK_LDW];
  __shared__ unsigned short gst[128 * GT_LDW];
  __shared__ unsigned short Ss[64 * SS_LDW];

  const int tid = threadIdx.x;
  const int m0 = blockIdx.x * 64;
  const int h = blockIdx.y;
  const size_t gbase = (size_t)m0 * 2048 + (size_t)h * 128;

  #pragma unroll
  for (int it = 0; it < 4; it++) {
    int e = tid + it * 256;
    int i = e >> 4;
    int c = (e & 15) << 3;
    size_t g = gbase + (size_t)i * 2048 + c;
    *(uint4*)&qs[i * QK_LDW + c] = *(const uint4*)&qn[g];
    *(uint4*)&ks[i * QK_LDW + c] = *(const uint4*)&kn[g];
    uint4 gvv = *(const uint4*)&gvp[g];
    unsigned short tmp[8];
    *(uint4*)tmp = gvv;
    #pragma unroll
    for (int t = 0; t < 8; t++) gst[(c + t) * GT_LDW + i] = tmp[t];
  }
  __syncthreads();

  {
    const int rr = tid >> 2;
    const int seg = (tid & 3) * 32;
    float ssq = 0.f, ssk = 0.f;
    #pragma unroll
    for (int k2 = 0; k2 < 32; k2 += 2) {
      unsigned uq = *(const unsigned*)&qs[rr * QK_LDW + seg + k2];
      unsigned uk = *(const unsigned*)&ks[rr * QK_LDW + seg + k2];
      float a = bf2f((unsigned short)(uq & 0xffff)), b = bf2f((unsigned short)(uq >> 16));
      float c2 = bf2f((unsigned short)(uk & 0xffff)), d2 = bf2f((unsigned short)(uk >> 16));
      ssq += a * a + b * b;
      ssk += c2 * c2 + d2 * d2;
    }
    ssq += __shfl_xor(ssq, 1); ssq += __shfl_xor(ssq, 2);
    ssk += __shfl_xor(ssk, 1); ssk += __shfl_xor(ssk, 2);
    float iq = rsqrtf(fmaxf(ssq, 1e-24f));
    float ik = rsqrtf(fmaxf(ssk, 1e-24f));
    #pragma unroll
    for (int k2 = 0; k2 < 32; k2 += 2) {
      unsigned uq = *(const unsigned*)&qs[rr * QK_LDW + seg + k2];
      unsigned uk = *(const unsigned*)&ks[rr * QK_LDW + seg + k2];
      float a = bf2f((unsigned short)(uq & 0xffff)), b = bf2f((unsigned short)(uq >> 16));
      float c2 = bf2f((unsigned short)(uk & 0xffff)), d2 = bf2f((unsigned short)(uk >> 16));
      *(unsigned*)&qs[rr * QK_LDW + seg + k2] = pk2(a * iq, b * iq);
      *(unsigned*)&ks[rr * QK_LDW + seg + k2] = pk2(c2 * ik, d2 * ik);
    }
  }
  __syncthreads();

  const int w = tid >> 6;
  const int lane = tid & 63;
  const int quad = lane >> 4, l16 = lane & 15;

  {
    f32x4 acc[4] = {};
    #pragma unroll
    for (int kst = 0; kst < 4; kst++) {
      bf16x8 a = *(const bf16x8*)&qs[(w * 16 + l16) * QK_LDW + kst * 32 + (quad << 3)];
      #pragma unroll
      for (int ni = 0; ni < 4; ni++) {
        bf16x8 b = *(const bf16x8*)&ks[(ni * 16 + l16) * QK_LDW + kst * 32 + (quad << 3)];
        acc[ni] = __builtin_amdgcn_mfma_f32_16x16x32_bf16(a, b, acc[ni], 0, 0, 0);
      }
    }
    #pragma unroll
    for (int ni = 0; ni < 4; ni++)
      #pragma unroll
      for (int r = 0; r < 4; r++) {
        int row = w * 16 + quad * 4 + r;
        int col = ni * 16 + l16;
        float val = (col <= row) ? acc[ni][r] : 0.f;
        Ss[row * SS_LDW + col] = f2bf(val);
      }
  }
  __syncthreads();

  {
    f32x4 acc[8] = {};
    #pragma unroll
    for (int kst = 0; kst < 2; kst++) {
      bf16x8 a = *(const bf16x8*)&Ss[(w * 16 + l16) * SS_LDW + kst * 32 + (quad << 3)];
      #pragma unroll
      for (int nd = 0; nd < 8; nd++) {
        bf16x8 b = *(const bf16x8*)&gst[(nd * 16 + l16) * GT_LDW + kst * 32 + (quad << 3)];
        acc[nd] = __builtin_amdgcn_mfma_f32_16x16x32_bf16(a, b, acc[nd], 0, 0, 0);
      }
    }
    #pragma unroll
    for (int nd = 0; nd < 8; nd++)
      #pragma unroll
      for (int r = 0; r < 4; r++) {
        int row = w * 16 + quad * 4 + r;
        int col = nd * 16 + l16;
        size_t g = gbase + (size_t)row * 2048 + col;
        float gt = bf2f(gate[g]);
        y[g] = f2bf(acc[nd][r] * gt);
      }
  }
}

// --------------------------------------------------------------- launch ---
extern "C" void kernel_launch(void* const* d_in, const int* in_sizes, int n_in,
                              void* d_out, int out_size, void* d_ws, size_t ws_size,
                              hipStream_t stream) {
  const float* hs   = (const float*)d_in[0];
  const float* q_w  = (const float*)d_in[1];
  const float* q_b  = (const float*)d_in[2];
  const float* k_w  = (const float*)d_in[3];
  const float* k_b  = (const float*)d_in[4];
  const float* v_w  = (const float*)d_in[5];
  const float* v_b  = (const float*)d_in[6];
  const float* b_w  = (const float*)d_in[9];
  const float* b_b  = (const float*)d_in[10];
  const float* og_w = (const float*)d_in[11];
  const float* o_w  = (const float*)d_in[12];
  const float* o_b  = (const float*)d_in[13];

  const int M = 16384, K = 2048;
  const size_t MB64 = 67108864;         // one [M,2048] bf16 buffer

  const size_t OFF_HSB  = 4 * MB64;
  const size_t OFF_WCAT = OFF_HSB + MB64;
  const size_t OFF_OWB  = OFF_WCAT + 33554432;
  const size_t OFF_BETA = OFF_OWB + 8388608;
  const size_t OFF_BIAS = OFF_BETA + 1048576;
  const size_t NEED     = OFF_BIAS + 32768;

  char* ws = (char*)d_ws;

  if (ws_size >= NEED) {
    unsigned short* qy   = (unsigned short*)ws;
    unsigned short* knb  = (unsigned short*)(ws + MB64);
    unsigned short* gv   = (unsigned short*)(ws + 2 * MB64);
    unsigned short* gate = (unsigned short*)(ws + 3 * MB64);
    unsigned short* hsb  = (unsigned short*)(ws + OFF_HSB);
    unsigned short* wcat = (unsigned short*)(ws + OFF_WCAT);
    unsigned short* owb  = (unsigned short*)(ws + OFF_OWB);
    float*          beta = (float*)(ws + OFF_BETA);
    float*          bias = (float*)(ws + OFF_BIAS);

    const int NW = 4194304;  // elems per 2048x2048 weight
    cvt_bf16<<<NW / 2048, 256, 0, stream>>>(q_w,  wcat,          NW);
    cvt_bf16<<<NW / 2048, 256, 0, stream>>>(k_w,  wcat + NW,     NW);
    cvt_bf16<<<NW / 2048, 256, 0, stream>>>(v_w,  wcat + 2 * NW, NW);
    cvt_bf16<<<NW / 2048, 256, 0, stream>>>(og_w, wcat + 3 * NW, NW);
    cvt_bf16<<<NW / 2048, 256, 0, stream>>>(o_w,  owb,           NW);
    build_bias<<<32, 256, 0, stream>>>(q_b, k_b, v_b, bias);
    beta_kernel<<<M, 256, 0, stream>>>(hs, b_w, b_b, beta, hsb);  // + hs->bf16

    gemm256<0, 8192, 2048><<<dim3(32, 64), 512, 0, stream>>>(
        hsb, wcat, bias, beta, qy);

    attn_kernel<<<dim3(256, 16), 256, 0, stream>>>(qy, knb, gv, gate, qy);

    gemm256<3, 2048, 2048><<<dim3(8, 64), 512, 0, stream>>>(
        qy, owb, o_b, nullptr, (float*)d_out);
  } else {
    // round-1 fallback (f32 pack staging), known-correct
    unsigned short* qy   = (unsigned short*)ws;
    unsigned short* knb  = (unsigned short*)(ws + MB64);
    unsigned short* gv   = (unsigned short*)(ws + 2 * MB64);
    unsigned short* gate = (unsigned short*)(ws + 3 * MB64);
    float*          beta = (float*)(ws + 4 * MB64);

    beta_kernel<<<M, 256, 0, stream>>>(hs, b_w, b_b, beta, nullptr);
    dim3 gg(16, 128);
    gemm_bt<0, false><<<gg, 256, 0, stream>>>(hs, q_w, q_b, nullptr, qy, M, 2048, K);
    gemm_bt<0, false><<<gg, 256, 0, stream>>>(hs, k_w, k_b, nullptr, knb, M, 2048, K);
    gemm_bt<1, false><<<gg, 256, 0, stream>>>(hs, v_w, v_b, beta, gv, M, 2048, K);
    gemm_bt<2, false><<<gg, 256, 0, stream>>>(hs, og_w, nullptr, nullptr, gate, M, 2048, K);
    attn_kernel<<<dim3(256, 16), 256, 0, stream>>>(qy, knb, gv, gate, qy);
    gemm_bt<3, true><<<gg, 256, 0, stream>>>(qy, o_w, o_b, nullptr, (float*)d_out, M, 2048, K);
  }
}

// Round 4
// 1137.105 us; speedup vs baseline: 1.1401x; 1.1401x over previous
//
#include <hip/hip_runtime.h>

// ChunkwiseDeltaAttention (MI355X/gfx950) — round 7
// B=4 L=4096 H=2048 NH=16 D=128 C=64 -> M=16384, K=2048
//
// Fast path:
//   beta_kernel: beta = softplus(hs @ b_w^T + b_b), AND hs -> bf16 hsb (fused)
//   cvt: {q,k,v,og}_w -> bf16 wcat [8192,2048]; o_w -> owb
//   gemm256<0,8192>: [qy|kn|gv|gate] = hsb @ wcat^T (+bias), fused epi
//   attn: l2norm in LDS, S=qk^T (MFMA), causal mask, O=S gv, *gate
//   gemm256<3,2048>: out = y @ o_w^T + o_b -> f32 d_out
//
// GEMM round 7 — faithful port of the verified 256^2 8-phase template:
//   * BK=64, 4 phases per K-step, 16 MFMA each, quadrant rotation:
//       p0: read A-lo(8)+B-lo(4), MFMA acc[0..3][0..1]
//       p1: read B-hi(4),         MFMA acc[0..3][2..3]   (A-lo reused from regs)
//       p2: read A-hi(8),         MFMA acc[4..7][2..3]   (B-hi reused)
//       p3: no reads,             MFMA acc[4..7][0..1]   (A-hi,B-lo reused)
//     -> 24 ds_read_b128 per BK=64 (HALF the LDS traffic/FLOP of round 6)
//   * 2 LDS buffers x {A-X,A-Y,B-X,B-Y} 16KB regions; each phase stages one
//     half-tile (2 cp16/thread) into a region DEAD since a prior phase:
//       p0: A-Y(t+1)->other buf (dead since t-1);  p1: A-X(t+2)->cur (dead p0)
//       p2: B-X(t+2)->cur (dead p0);               p3: B-Y(t+2)->cur (dead p1)
//     Completion: half staged at slot s is read >=6 slots later; one
//     {vmcnt(6); barrier} per K-step (end of p3) proves (all waves lockstep,
//     uniform 2 loads/slot): everything but the newest 3 slots is complete.
//   * 3-bit XOR swizzle for 128B rows: phys 16B chunk = (ksub*4+quad)^ (idx&7)
//     on the read side, source chunk = c ^ (idx&7) on the stage side (linear
//     LDS dest per global_load_lds rule). 8 distinct slots per aligned 8-lane
//     group -> conflict-free (round-5's 2-bit sigma only covered 64B rows).
//   * setprio(1) around each 16-MFMA cluster; double barrier per phase.

typedef __bf16 bf16x8 __attribute__((ext_vector_type(8)));
typedef float f32x4 __attribute__((ext_vector_type(4)));

typedef __attribute__((address_space(1))) const unsigned int g_u32;
typedef __attribute__((address_space(3))) unsigned int l_u32;

__device__ __forceinline__ void cp16(const unsigned short* g, unsigned short* l) {
  __builtin_amdgcn_global_load_lds((g_u32*)g, (l_u32*)l, 16, 0, 0);
}

__device__ __forceinline__ unsigned short f2bf(float x) {
  unsigned u = __builtin_bit_cast(unsigned, x);
  u += 0x7fffu + ((u >> 16) & 1u);          // RNE
  return (unsigned short)(u >> 16);
}
__device__ __forceinline__ float bf2f(unsigned short h) {
  return __builtin_bit_cast(float, (unsigned)h << 16);
}
__device__ __forceinline__ unsigned pk2(float a, float b) {
  return (unsigned)f2bf(a) | ((unsigned)f2bf(b) << 16);
}

// ------------------------------------------------------------- convert ----
__global__ __launch_bounds__(256) void cvt_bf16(const float* __restrict__ in,
                                                unsigned short* __restrict__ out,
                                                int n) {
  int i = (blockIdx.x * 256 + threadIdx.x) * 8;
  if (i >= n) return;
  float4 f0 = *(const float4*)(in + i);
  float4 f1 = *(const float4*)(in + i + 4);
  uint4 u;
  u.x = pk2(f0.x, f0.y); u.y = pk2(f0.z, f0.w);
  u.z = pk2(f1.x, f1.y); u.w = pk2(f1.z, f1.w);
  *(uint4*)(out + i) = u;
}

__global__ __launch_bounds__(256) void build_bias(
    const float* __restrict__ qb, const float* __restrict__ kb,
    const float* __restrict__ vb, float* __restrict__ bias_cat) {
  int i = blockIdx.x * 256 + threadIdx.x;   // 0..8191
  float v = 0.f;
  if (i < 2048) v = qb[i];
  else if (i < 4096) v = kb[i - 2048];
  else if (i < 6144) v = vb[i - 4096];
  bias_cat[i] = v;
}

// ------------------------------------------------- beta (+ hs->bf16) ------
__global__ __launch_bounds__(256) void beta_kernel(
    const float* __restrict__ hs, const float* __restrict__ bw,
    const float* __restrict__ bb, float* __restrict__ beta,
    unsigned short* __restrict__ hsb) {
  __shared__ float row[2048];
  __shared__ float part[16][17];
  const int m = blockIdx.x;
  const float* src = hs + (size_t)m * 2048;
  for (int i = threadIdx.x; i < 512; i += 256)
    ((float4*)row)[i] = ((const float4*)src)[i];
  __syncthreads();
  if (hsb) {  // fused f32->bf16 of this row
    int e = threadIdx.x * 8;
    uint4 u;
    u.x = pk2(row[e], row[e + 1]);     u.y = pk2(row[e + 2], row[e + 3]);
    u.z = pk2(row[e + 4], row[e + 5]); u.w = pk2(row[e + 6], row[e + 7]);
    *(uint4*)(hsb + (size_t)m * 2048 + e) = u;
  }
  const int h = threadIdx.x >> 4, j = threadIdx.x & 15;
  const float* w = bw + h * 2048;
  float s = 0.f;
  #pragma unroll 8
  for (int kk = 0; kk < 128; kk++) {
    int k = j + (kk << 4);
    s += row[k] * w[k];
  }
  part[h][j] = s;
  __syncthreads();
  if (threadIdx.x < 16) {
    int hh = threadIdx.x;
    float t = bb[hh];
    #pragma unroll
    for (int j2 = 0; j2 < 16; j2++) t += part[hh][j2];
    beta[(size_t)m * 16 + hh] = fmaxf(t, 0.f) + log1pf(__expf(-fabsf(t)));
  }
}

// ------------------------------ GEMM 256x256, BK=64, 4-phase quadrant ------
// C[m,n] = sum_k A[m,k]*B[n,k], bf16 in. 512 threads = 8 waves (2Mx4N),
// per-wave C = 128x64 = 8mi x 4ni fragments.
// LDS: S[2 bufs][AX|AY|BX|BY, 16KB each] = 128 KiB.
//   A-X region holds A rows {0-63}U{128-191} (the mi0-3 read-set: wm*64+idx),
//   A-Y rows {64-127}U{192-255}; B-X rows {wn*64+0..31} (ni0-1 set, idx =
//   wn*32+ni*16+l16), B-Y rows {wn*64+32..63}.
// Region-row idx in [0,128); stage thread (sidx=tid>>3, c=tid&7) writes
// 16B chunk c of rows sidx (cp#0) and sidx+64 (cp#1) at LINEAR dest
// region + tid*16B (+8KB), with XOR-swizzled global source chunk
// c ^ (sidx&7) (sidx+64 has the same sigma). Reads use phys chunk
// (ksub*4+quad) ^ (l16&7)  (idx&7 == l16&7 for all fragments).
template <int EPI, int N, int K>
__global__ __launch_bounds__(512, 2) void gemm256(
    const unsigned short* __restrict__ A, const unsigned short* __restrict__ Bw,
    const float* __restrict__ bias, const float* __restrict__ beta,
    void* __restrict__ Cv) {
  constexpr int NT = K / 64;
  static_assert(NT >= 3, "pipeline needs >=3 K-steps");
  __shared__ __align__(16) unsigned short S[2 * 32768];   // 128 KiB
  const int tid = threadIdx.x;
  const int m0 = blockIdx.y * 256;
  const int n0 = blockIdx.x * 256;
  const int wid = tid >> 6, lane = tid & 63;
  const int wm = wid >> 2, wn = wid & 3;
  const int quad = lane >> 4, l16 = lane & 15;

  // ---- staging maps ----
  const int sidx = tid >> 3;                  // 0..63
  const int sc = tid & 7;                     // 16B chunk
  const int scol = ((sc ^ (sidx & 7)) << 3);  // swizzled src elem offset
  const unsigned short* pA = A + (size_t)(m0 + sidx) * K + scol;
  const int rbx = ((sidx >> 5) << 6) + (sidx & 31);       // B-X row for sidx
  const unsigned short* pB = Bw + (size_t)(n0 + rbx) * K + scol;

  // stage one half-tile (16KB): rows {sidx, sidx+128} of the region's
  // row-list; dest = region + tid*16B and +8KB (linear, cp16 rule).
  auto STG = [&](int roff /*shorts*/, const unsigned short* src) {
    cp16(src, S + roff + tid * 8);
    cp16(src + (size_t)128 * K, S + roff + 4096 + tid * 8);
  };

  // ---- read maps ----
  const int sig = l16 & 7;
  const int ck0 = ((quad ^ sig) << 4);             // ksub0 phys chunk (bytes)
  const int ck1 = (((4 + quad) ^ sig) << 4);       // ksub1
  const int aro = (wm * 64 + l16) * 128;           // byte offset in A region
  const int bro = (wn * 32 + l16) * 128;           // byte offset in B region

  f32x4 acc[8][4] = {};
  bf16x8 aL[4][2], aH[4][2], bX[2][2], bY[2][2];

  // ---- prologue: K0 {AX,AY,BX,BY}, K1 {AX,BX,BY}; AY(1) staged at t=0 p0.
  STG(0,             pA);
  STG(8192,          pA + (size_t)64 * K);
  STG(16384,         pB);
  STG(24576,         pB + (size_t)32 * K);
  STG(32768,         pA + 64);
  STG(32768 + 16384, pB + 64);
  STG(32768 + 24576, pB + (size_t)32 * K + 64);
  asm volatile("s_waitcnt vmcnt(6)" ::: "memory");  // all of K0 complete
  __builtin_amdgcn_s_barrier();

  for (int t = 0; t < NT; ++t) {
    const int cur = (t & 1) << 15;        // short offset of current buf
    const int nxt = 32768 - cur;
    const char* B0 = (const char*)S + cur * 2;
    const int koff1 = (t + 1 < NT ? t + 1 : NT - 1) * 64;
    const int koff2 = (t + 2 < NT ? t + 2 : NT - 1) * 64;

    // -------- phase 0: read A-lo + B-lo; stage A-Y(t+1) --------
    #pragma unroll
    for (int mi = 0; mi < 4; mi++) {
      aL[mi][0] = *(const bf16x8*)(B0 + aro + mi * 2048 + ck0);
      aL[mi][1] = *(const bf16x8*)(B0 + aro + mi * 2048 + ck1);
    }
    #pragma unroll
    for (int ni = 0; ni < 2; ni++) {
      bX[ni][0] = *(const bf16x8*)(B0 + 32768 + bro + ni * 2048 + ck0);
      bX[ni][1] = *(const bf16x8*)(B0 + 32768 + bro + ni * 2048 + ck1);
    }
    STG(nxt + 8192, pA + (size_t)64 * K + koff1);
    __builtin_amdgcn_s_barrier();
    __builtin_amdgcn_s_setprio(1);
    #pragma unroll
    for (int k = 0; k < 2; k++)
      #pragma unroll
      for (int mi = 0; mi < 4; mi++)
        #pragma unroll
        for (int ni = 0; ni < 2; ni++)
          acc[mi][ni] = __builtin_amdgcn_mfma_f32_16x16x32_bf16(
              aL[mi][k], bX[ni][k], acc[mi][ni], 0, 0, 0);
    __builtin_amdgcn_s_setprio(0);
    __builtin_amdgcn_s_barrier();

    // -------- phase 1: read B-hi; stage A-X(t+2) (dead since p0) --------
    #pragma unroll
    for (int ni = 0; ni < 2; ni++) {
      bY[ni][0] = *(const bf16x8*)(B0 + 49152 + bro + ni * 2048 + ck0);
      bY[ni][1] = *(const bf16x8*)(B0 + 49152 + bro + ni * 2048 + ck1);
    }
    STG(cur, pA + koff2);
    __builtin_amdgcn_s_barrier();
    __builtin_amdgcn_s_setprio(1);
    #pragma unroll
    for (int k = 0; k < 2; k++)
      #pragma unroll
      for (int mi = 0; mi < 4; mi++)
        #pragma unroll
        for (int ni = 0; ni < 2; ni++)
          acc[mi][2 + ni] = __builtin_amdgcn_mfma_f32_16x16x32_bf16(
              aL[mi][k], bY[ni][k], acc[mi][2 + ni], 0, 0, 0);
    __builtin_amdgcn_s_setprio(0);
    __builtin_amdgcn_s_barrier();

    // -------- phase 2: read A-hi; stage B-X(t+2) (dead since p0) --------
    #pragma unroll
    for (int mi = 0; mi < 4; mi++) {
      aH[mi][0] = *(const bf16x8*)(B0 + 16384 + aro + mi * 2048 + ck0);
      aH[mi][1] = *(const bf16x8*)(B0 + 16384 + aro + mi * 2048 + ck1);
    }
    STG(cur + 16384, pB + koff2);
    __builtin_amdgcn_s_barrier();
    __builtin_amdgcn_s_setprio(1);
    #pragma unroll
    for (int k = 0; k < 2; k++)
      #pragma unroll
      for (int mi = 0; mi < 4; mi++)
        #pragma unroll
        for (int ni = 0; ni < 2; ni++)
          acc[4 + mi][2 + ni] = __builtin_amdgcn_mfma_f32_16x16x32_bf16(
              aH[mi][k], bY[ni][k], acc[4 + mi][2 + ni], 0, 0, 0);
    __builtin_amdgcn_s_setprio(0);
    __builtin_amdgcn_s_barrier();

    // -------- phase 3: no reads; stage B-Y(t+2) (dead since p1) --------
    STG(cur + 24576, pB + (size_t)32 * K + koff2);
    __builtin_amdgcn_s_setprio(1);
    #pragma unroll
    for (int k = 0; k < 2; k++)
      #pragma unroll
      for (int mi = 0; mi < 4; mi++)
        #pragma unroll
        for (int ni = 0; ni < 2; ni++)
          acc[4 + mi][ni] = __builtin_amdgcn_mfma_f32_16x16x32_bf16(
              aH[mi][k], bX[ni][k], acc[4 + mi][ni], 0, 0, 0);
    __builtin_amdgcn_s_setprio(0);
    asm volatile("s_waitcnt vmcnt(6)" ::: "memory");   // K(t+1) fully ready
    __builtin_amdgcn_s_barrier();
  }
  asm volatile("s_waitcnt vmcnt(0)" ::: "memory");     // drain tail stages

  // epilogue; C/D layout: col=lane&15, row=quad*4+reg
  if (EPI == 0) {
    const int mode = n0 >> 11;              // 0:q 1:k 2:v 3:gate (256 | 2048)
    unsigned short* outp =
        (unsigned short*)Cv + (size_t)mode * ((size_t)16384 * 2048);
    const int head = ((n0 + wn * 64) >> 7) & 15;   // head uniform per wave
    #pragma unroll
    for (int mi = 0; mi < 8; mi++) {
      #pragma unroll
      for (int r = 0; r < 4; r++) {
        const int row = m0 + wm * 128 + mi * 16 + quad * 4 + r;
        const float bsc = (mode == 2) ? beta[(size_t)row * 16 + head] : 1.f;
        #pragma unroll
        for (int ni = 0; ni < 4; ni++) {
          const int col = n0 + wn * 64 + ni * 16 + l16;
          float x = acc[mi][ni][r] + bias[col];
          if (mode == 2) x *= bsc;
          if (mode == 3) x = x / (1.f + __expf(-x));
          outp[(size_t)row * 2048 + (col & 2047)] = f2bf(x);
        }
      }
    }
  } else {
    #pragma unroll
    for (int mi = 0; mi < 8; mi++)
      #pragma unroll
      for (int r = 0; r < 4; r++) {
        const int row = m0 + wm * 128 + mi * 16 + quad * 4 + r;
        #pragma unroll
        for (int ni = 0; ni < 4; ni++) {
          const int col = n0 + wn * 64 + ni * 16 + l16;
          ((float*)Cv)[(size_t)row * N + col] = acc[mi][ni][r] + bias[col];
        }
      }
  }
}

// --------------------------------------------- fallback GEMM (round 1) ----
constexpr int GLDW = 40;
template <int EPI, bool ABF16>
__global__ __launch_bounds__(256) void gemm_bt(
    const void* __restrict__ Av, const float* __restrict__ Bw,
    const float* __restrict__ bias, const float* __restrict__ beta,
    void* __restrict__ Cv, int M, int N, int K) {
  __shared__ unsigned short As[128 * GLDW];
  __shared__ unsigned short Bs[128 * GLDW];
  const int tid = threadIdx.x;
  const int m0 = blockIdx.y * 128;
  const int n0 = blockIdx.x * 128;
  const int wid = tid >> 6, lane = tid & 63;
  const int wm = wid >> 1, wn = wid & 1;
  const int quad = lane >> 4, l16 = lane & 15;
  const int srow = tid >> 1, skh = (tid & 1) << 4;

  f32x4 acc[4][4] = {};
  const float* Bg = Bw + (size_t)(n0 + srow) * K + skh;

  for (int kb = 0; kb < K; kb += 32) {
    if (ABF16) {
      const unsigned short* Ag =
          (const unsigned short*)Av + (size_t)(m0 + srow) * K + kb + skh;
      uint4 u0 = ((const uint4*)Ag)[0];
      uint4 u1 = ((const uint4*)Ag)[1];
      uint4* d = (uint4*)&As[srow * GLDW + skh];
      d[0] = u0; d[1] = u1;
    } else {
      const float* Ag = (const float*)Av + (size_t)(m0 + srow) * K + kb + skh;
      float4 f0 = ((const float4*)Ag)[0];
      float4 f1 = ((const float4*)Ag)[1];
      float4 f2 = ((const float4*)Ag)[2];
      float4 f3 = ((const float4*)Ag)[3];
      unsigned* d = (unsigned*)&As[srow * GLDW + skh];
      d[0] = pk2(f0.x, f0.y); d[1] = pk2(f0.z, f0.w);
      d[2] = pk2(f1.x, f1.y); d[3] = pk2(f1.z, f1.w);
      d[4] = pk2(f2.x, f2.y); d[5] = pk2(f2.z, f2.w);
      d[6] = pk2(f3.x, f3.y); d[7] = pk2(f3.z, f3.w);
    }
    {
      const float* Bgk = Bg + kb;
      float4 f0 = ((const float4*)Bgk)[0];
      float4 f1 = ((const float4*)Bgk)[1];
      float4 f2 = ((const float4*)Bgk)[2];
      float4 f3 = ((const float4*)Bgk)[3];
      unsigned* d = (unsigned*)&Bs[srow * GLDW + skh];
      d[0] = pk2(f0.x, f0.y); d[1] = pk2(f0.z, f0.w);
      d[2] = pk2(f1.x, f1.y); d[3] = pk2(f1.z, f1.w);
      d[4] = pk2(f2.x, f2.y); d[5] = pk2(f2.z, f2.w);
      d[6] = pk2(f3.x, f3.y); d[7] = pk2(f3.z, f3.w);
    }
    __syncthreads();
    bf16x8 af[4], bfr[4];
    #pragma unroll
    for (int mi = 0; mi < 4; mi++)
      af[mi] = *(const bf16x8*)&As[(wm * 64 + mi * 16 + l16) * GLDW + (quad << 3)];
    #pragma unroll
    for (int ni = 0; ni < 4; ni++)
      bfr[ni] = *(const bf16x8*)&Bs[(wn * 64 + ni * 16 + l16) * GLDW + (quad << 3)];
    #pragma unroll
    for (int mi = 0; mi < 4; mi++)
      #pragma unroll
      for (int ni = 0; ni < 4; ni++)
        acc[mi][ni] = __builtin_amdgcn_mfma_f32_16x16x32_bf16(
            af[mi], bfr[ni], acc[mi][ni], 0, 0, 0);
    __syncthreads();
  }

  #pragma unroll
  for (int mi = 0; mi < 4; mi++) {
    #pragma unroll
    for (int r = 0; r < 4; r++) {
      const int row = m0 + wm * 64 + mi * 16 + quad * 4 + r;
      float bsc = 1.f;
      if (EPI == 1) bsc = beta[(size_t)row * 16 + blockIdx.x];
      #pragma unroll
      for (int ni = 0; ni < 4; ni++) {
        const int col = n0 + wn * 64 + ni * 16 + l16;
        float x = acc[mi][ni][r];
        if (EPI != 2) x += bias[col];
        if (EPI == 1) x *= bsc;
        if (EPI == 2) x = x / (1.f + __expf(-x));
        if (EPI == 3)
          ((float*)Cv)[(size_t)row * N + col] = x;
        else
          ((unsigned short*)Cv)[(size_t)row * N + col] = f2bf(x);
      }
    }
  }
}

// ----------------------------------------------------------- attention ----
constexpr int QK_LDW = 132;  // 264B = 66 banks = 2 mod 32: lanes spread
constexpr int GT_LDW = 66;   // 132B = 33 banks = 1 mod 32: write 16-way -> 4-way
constexpr int SS_LDW = 68;   // 136B = 34 banks = 2 mod 32

__global__ __launch_bounds__(256) void attn_kernel(
    const unsigned short* __restrict__ qn, const unsigned short* __restrict__ kn,
    const unsigned short* __restrict__ gvp, const unsigned short* __restrict__ gate,
    unsigned short* __restrict__ y) {
  __shared__ unsigned short qs[64 * QK_LDW];
  __shared__ unsigned short ks[64 * QK_LDW];
  __shared__ unsigned short gst[128 * GT_LDW];
  __shared__ unsigned short Ss[64 * SS_LDW];

  const int tid = threadIdx.x;
  const int m0 = blockIdx.x * 64;
  const int h = blockIdx.y;
  const size_t gbase = (size_t)m0 * 2048 + (size_t)h * 128;

  #pragma unroll
  for (int it = 0; it < 4; it++) {
    int e = tid + it * 256;
    int i = e >> 4;
    int c = (e & 15) << 3;
    size_t g = gbase + (size_t)i * 2048 + c;
    *(uint4*)&qs[i * QK_LDW + c] = *(const uint4*)&qn[g];
    *(uint4*)&ks[i * QK_LDW + c] = *(const uint4*)&kn[g];
    uint4 gvv = *(const uint4*)&gvp[g];
    unsigned short tmp[8];
    *(uint4*)tmp = gvv;
    #pragma unroll
    for (int t = 0; t < 8; t++) gst[(c + t) * GT_LDW + i] = tmp[t];
  }
  __syncthreads();

  {
    const int rr = tid >> 2;
    const int seg = (tid & 3) * 32;
    float ssq = 0.f, ssk = 0.f;
    #pragma unroll
    for (int k2 = 0; k2 < 32; k2 += 2) {
      unsigned uq = *(const unsigned*)&qs[rr * QK_LDW + seg + k2];
      unsigned uk = *(const unsigned*)&ks[rr * QK_LDW + seg + k2];
      float a = bf2f((unsigned short)(uq & 0xffff)), b = bf2f((unsigned short)(uq >> 16));
      float c2 = bf2f((unsigned short)(uk & 0xffff)), d2 = bf2f((unsigned short)(uk >> 16));
      ssq += a * a + b * b;
      ssk += c2 * c2 + d2 * d2;
    }
    ssq += __shfl_xor(ssq, 1); ssq += __shfl_xor(ssq, 2);
    ssk += __shfl_xor(ssk, 1); ssk += __shfl_xor(ssk, 2);
    float iq = rsqrtf(fmaxf(ssq, 1e-24f));
    float ik = rsqrtf(fmaxf(ssk, 1e-24f));
    #pragma unroll
    for (int k2 = 0; k2 < 32; k2 += 2) {
      unsigned uq = *(const unsigned*)&qs[rr * QK_LDW + seg + k2];
      unsigned uk = *(const unsigned*)&ks[rr * QK_LDW + seg + k2];
      float a = bf2f((unsigned short)(uq & 0xffff)), b = bf2f((unsigned short)(uq >> 16));
      float c2 = bf2f((unsigned short)(uk & 0xffff)), d2 = bf2f((unsigned short)(uk >> 16));
      *(unsigned*)&qs[rr * QK_LDW + seg + k2] = pk2(a * iq, b * iq);
      *(unsigned*)&ks[rr * QK_LDW + seg + k2] = pk2(c2 * ik, d2 * ik);
    }
  }
  __syncthreads();

  const int w = tid >> 6;
  const int lane = tid & 63;
  const int quad = lane >> 4, l16 = lane & 15;

  {
    f32x4 acc[4] = {};
    #pragma unroll
    for (int kst = 0; kst < 4; kst++) {
      bf16x8 a = *(const bf16x8*)&qs[(w * 16 + l16) * QK_LDW + kst * 32 + (quad << 3)];
      #pragma unroll
      for (int ni = 0; ni < 4; ni++) {
        bf16x8 b = *(const bf16x8*)&ks[(ni * 16 + l16) * QK_LDW + kst * 32 + (quad << 3)];
        acc[ni] = __builtin_amdgcn_mfma_f32_16x16x32_bf16(a, b, acc[ni], 0, 0, 0);
      }
    }
    #pragma unroll
    for (int ni = 0; ni < 4; ni++)
      #pragma unroll
      for (int r = 0; r < 4; r++) {
        int row = w * 16 + quad * 4 + r;
        int col = ni * 16 + l16;
        float val = (col <= row) ? acc[ni][r] : 0.f;
        Ss[row * SS_LDW + col] = f2bf(val);
      }
  }
  __syncthreads();

  {
    f32x4 acc[8] = {};
    #pragma unroll
    for (int kst = 0; kst < 2; kst++) {
      bf16x8 a = *(const bf16x8*)&Ss[(w * 16 + l16) * SS_LDW + kst * 32 + (quad << 3)];
      #pragma unroll
      for (int nd = 0; nd < 8; nd++) {
        bf16x8 b = *(const bf16x8*)&gst[(nd * 16 + l16) * GT_LDW + kst * 32 + (quad << 3)];
        acc[nd] = __builtin_amdgcn_mfma_f32_16x16x32_bf16(a, b, acc[nd], 0, 0, 0);
      }
    }
    #pragma unroll
    for (int nd = 0; nd < 8; nd++)
      #pragma unroll
      for (int r = 0; r < 4; r++) {
        int row = w * 16 + quad * 4 + r;
        int col = nd * 16 + l16;
        size_t g = gbase + (size_t)row * 2048 + col;
        float gt = bf2f(gate[g]);
        y[g] = f2bf(acc[nd][r] * gt);
      }
  }
}

// --------------------------------------------------------------- launch ---
extern "C" void kernel_launch(void* const* d_in, const int* in_sizes, int n_in,
                              void* d_out, int out_size, void* d_ws, size_t ws_size,
                              hipStream_t stream) {
  const float* hs   = (const float*)d_in[0];
  const float* q_w  = (const float*)d_in[1];
  const float* q_b  = (const float*)d_in[2];
  const float* k_w  = (const float*)d_in[3];
  const float* k_b  = (const float*)d_in[4];
  const float* v_w  = (const float*)d_in[5];
  const float* v_b  = (const float*)d_in[6];
  const float* b_w  = (const float*)d_in[9];
  const float* b_b  = (const float*)d_in[10];
  const float* og_w = (const float*)d_in[11];
  const float* o_w  = (const float*)d_in[12];
  const float* o_b  = (const float*)d_in[13];

  const int M = 16384, K = 2048;
  const size_t MB64 = 67108864;         // one [M,2048] bf16 buffer

  const size_t OFF_HSB  = 4 * MB64;
  const size_t OFF_WCAT = OFF_HSB + MB64;
  const size_t OFF_OWB  = OFF_WCAT + 33554432;
  const size_t OFF_BETA = OFF_OWB + 8388608;
  const size_t OFF_BIAS = OFF_BETA + 1048576;
  const size_t NEED     = OFF_BIAS + 32768;

  char* ws = (char*)d_ws;

  if (ws_size >= NEED) {
    unsigned short* qy   = (unsigned short*)ws;
    unsigned short* knb  = (unsigned short*)(ws + MB64);
    unsigned short* gv   = (unsigned short*)(ws + 2 * MB64);
    unsigned short* gate = (unsigned short*)(ws + 3 * MB64);
    unsigned short* hsb  = (unsigned short*)(ws + OFF_HSB);
    unsigned short* wcat = (unsigned short*)(ws + OFF_WCAT);
    unsigned short* owb  = (unsigned short*)(ws + OFF_OWB);
    float*          beta = (float*)(ws + OFF_BETA);
    float*          bias = (float*)(ws + OFF_BIAS);

    const int NW = 4194304;  // elems per 2048x2048 weight
    cvt_bf16<<<NW / 2048, 256, 0, stream>>>(q_w,  wcat,          NW);
    cvt_bf16<<<NW / 2048, 256, 0, stream>>>(k_w,  wcat + NW,     NW);
    cvt_bf16<<<NW / 2048, 256, 0, stream>>>(v_w,  wcat + 2 * NW, NW);
    cvt_bf16<<<NW / 2048, 256, 0, stream>>>(og_w, wcat + 3 * NW, NW);
    cvt_bf16<<<NW / 2048, 256, 0, stream>>>(o_w,  owb,           NW);
    build_bias<<<32, 256, 0, stream>>>(q_b, k_b, v_b, bias);
    beta_kernel<<<M, 256, 0, stream>>>(hs, b_w, b_b, beta, hsb);  // + hs->bf16

    gemm256<0, 8192, 2048><<<dim3(32, 64), 512, 0, stream>>>(
        hsb, wcat, bias, beta, qy);

    attn_kernel<<<dim3(256, 16), 256, 0, stream>>>(qy, knb, gv, gate, qy);

    gemm256<3, 2048, 2048><<<dim3(8, 64), 512, 0, stream>>>(
        qy, owb, o_b, nullptr, (float*)d_out);
  } else {
    // round-1 fallback (f32 pack staging), known-correct
    unsigned short* qy   = (unsigned short*)ws;
    unsigned short* knb  = (unsigned short*)(ws + MB64);
    unsigned short* gv   = (unsigned short*)(ws + 2 * MB64);
    unsigned short* gate = (unsigned short*)(ws + 3 * MB64);
    float*          beta = (float*)(ws + 4 * MB64);

    beta_kernel<<<M, 256, 0, stream>>>(hs, b_w, b_b, beta, nullptr);
    dim3 gg(16, 128);
    gemm_bt<0, false><<<gg, 256, 0, stream>>>(hs, q_w, q_b, nullptr, qy, M, 2048, K);
    gemm_bt<0, false><<<gg, 256, 0, stream>>>(hs, k_w, k_b, nullptr, knb, M, 2048, K);
    gemm_bt<1, false><<<gg, 256, 0, stream>>>(hs, v_w, v_b, beta, gv, M, 2048, K);
    gemm_bt<2, false><<<gg, 256, 0, stream>>>(hs, og_w, nullptr, nullptr, gate, M, 2048, K);
    attn_kernel<<<dim3(256, 16), 256, 0, stream>>>(qy, knb, gv, gate, qy);
    gemm_bt<3, true><<<gg, 256, 0, stream>>>(qy, o_w, o_b, nullptr, (float*)d_out, M, 2048, K);
  }
}